// Round 15
// baseline (154.728 us; speedup 1.0000x reference)
//
#include <hip/hip_runtime.h>

namespace {
constexpr float kLrelu = 0.2f;
constexpr float kEps   = 1e-5f;
}

typedef short bf16x8 __attribute__((ext_vector_type(8)));
typedef float f32x4  __attribute__((ext_vector_type(4)));

union U4BF8 { uint4 u; bf16x8 v; };

// round-to-nearest-even f32 -> bf16 (inputs are finite)
static __device__ __forceinline__ unsigned f2bf(float x) {
  unsigned u = __float_as_uint(x);
  return (u + 0x7FFFu + ((u >> 16) & 1u)) >> 16;
}
static __device__ __forceinline__ unsigned packbf(float a, float b) {
  return f2bf(a) | (f2bf(b) << 16);
}

// Fully fused grouped conv (bf16 MFMA) + block-local BN + LeakyReLU + fold
// store -- BARRIER-FREE K-loop. Block = (g, zt): 64 z x ALL 512 m, 8 waves.
// Each wave owns m in [w*64,(w+1)*64): its raw patches, im2col gather and
// B-tile live in WAVE-PRIVATE LDS (DS ops are in-order within a wave -> no
// s_barrier needed). A-fragments are loaded straight from global into regs
// (L2-hot: reused 8 waves x 4 zt-blocks). Only the BN epilogue syncs.
__global__ __launch_bounds__(512, 2) void conv_bn_fused(
    const float* __restrict__ input,   // [32,128,64,64]
    const float* __restrict__ weight,  // [16384, 2048]  (k = nc*16 + ky*4 + kx)
    float* __restrict__ out,           // [32,256,32,32] FINAL (post BN+LReLU)
    const float* __restrict__ gamma,
    const float* __restrict__ beta)
{
  // [0,32KB): per-wave Bs tile (4KB each): 64 m-rows x 64B, XOR swizzle
  // [32KB,64KB): per-wave raw dbuf (2 x 2KB): 8 patches x 64 floats, row-XOR
  __shared__ __align__(16) char lds[65536];

  const int bid  = blockIdx.x;
  const int orig = (bid & 7) * 32 + (bid >> 3);   // XCD-chunked (256 % 8 == 0)
  const int g    = orig >> 2;                     // group 0..63
  const int zt   = orig & 3;                      // z tile 0..3
  const int hp = g >> 3, wp = g & 7;
  const int z0 = zt * 64;

  const int tid  = threadIdx.x;
  const int lane = tid & 63;
  const int w    = tid >> 6;                      // wave 0..7, m = w*64 + mlw
  const int llo  = lane & 15, lhi = lane >> 4;

  char*  const BsW   = lds + w * 4096;
  float* const rawW0 = (float*)(lds + 32768 + w * 4096);
  float* const rawW1 = rawW0 + 512;

  // -------- raw staging: 2 float4 tasks/lane (wave's 8 patches x 16 f4)
  const float* sPtrG[2];
  int sOffL[2];
#pragma unroll
  for (int t = 0; t < 2; ++t) {
    const int i  = t * 64 + lane;                 // 0..127
    const int pl = i >> 4;                        // patch 0..7
    const int q  = i & 15;
    const int py = q >> 1, h = q & 1;
    const int bl = w * 4 + (pl >> 1);             // batch 0..31
    const int nc = pl & 1;
    sPtrG[t] = input + ((size_t)bl * 128 + nc) * 4096
             + (hp * 8 + py) * 64 + wp * 8 + (h << 2);    // + ck*8192
    sOffL[t] = pl * 64 + ((py ^ (bl & 7)) << 3) + (h << 2);
  }

  // -------- A-fragment global pointers: lane -> (z-row zf*16+llo, k=lhi*8)
  const float* wfp[4];
#pragma unroll
  for (int zf = 0; zf < 4; ++zf)
    wfp[zf] = weight + ((size_t)(g * 256 + z0 + zf * 16 + llo)) * 2048 + lhi * 8;

  // -------- gather mapping: lane -> (bl_rel, oy, ky), 2 tasks (ncs)
  const int bl_r = lane >> 4;                     // 0..3
  const int oy_g = (lane >> 2) & 3;
  const int ky_g = lane & 3;
  const int blg  = w * 4 + bl_r;
  const int iy   = 2 * oy_g - 1 + ky_g;
  const unsigned rowm = ((unsigned)iy < 8u) ? 0xFFFFFFFFu : 0u;
  const int iyc  = iy < 0 ? 0 : (iy > 7 ? 7 : iy);
  const int gro0 = (bl_r * 2 + 0) * 64 + ((iyc ^ (blg & 7)) << 3);
  const int gro1 = gro0 + 64;                     // ncs=1 patch is +64 floats
  // B-write dsts: mlw = bl_r*16+oy*4+ox, byte col = ncs*32 + ky*8
  char* bwd[2][4];
#pragma unroll
  for (int ncs = 0; ncs < 2; ++ncs)
#pragma unroll
    for (int ox = 0; ox < 4; ++ox) {
      const int mlw = bl_r * 16 + oy_g * 4 + ox;
      const int gk  = ncs * 2 + (ky_g >> 1);
      bwd[ncs][ox] = BsW + mlw * 64 + ((gk ^ ((mlw >> 1) & 3)) << 4) + ((ky_g & 1) << 3);
    }

  // -------- B fragment read pointers (wave-local rows)
  const char* bfp[4];
#pragma unroll
  for (int mf = 0; mf < 4; ++mf) {
    const int mr = mf * 16 + llo;                 // 0..63
    bfp[mf] = BsW + mr * 64 + ((lhi ^ ((mr >> 1) & 3)) << 4);
  }

  f32x4 acc[4][4] = {};

  uint2 ub[2][4];
  auto gather = [&](const float* rw) {
#pragma unroll
    for (int ncs = 0; ncs < 2; ++ncs) {
      const int gro = ncs ? gro1 : gro0;
      const float4 r0 = *(const float4*)(rw + gro);
      const float4 r1 = *(const float4*)(rw + gro + 4);
      uint2 t;
      t.x = packbf(0.f, r0.x) & rowm;  t.y = packbf(r0.y, r0.z) & rowm;  ub[ncs][0] = t;
      t.x = packbf(r0.y, r0.z) & rowm; t.y = packbf(r0.w, r1.x) & rowm;  ub[ncs][1] = t;
      t.x = packbf(r0.w, r1.x) & rowm; t.y = packbf(r1.y, r1.z) & rowm;  ub[ncs][2] = t;
      t.x = packbf(r1.y, r1.z) & rowm; t.y = packbf(r1.w, 0.f) & rowm;   ub[ncs][3] = t;
    }
  };
  auto writeB = [&]() {
#pragma unroll
    for (int ncs = 0; ncs < 2; ++ncs)
#pragma unroll
      for (int ox = 0; ox < 4; ++ox) *(uint2*)bwd[ncs][ox] = ub[ncs][ox];
  };

  // -------- prologue: stage chunk 0; prefetch raw of chunk 1 into regs
  float4 r0t0 = *(const float4*)(sPtrG[0]);
  float4 r0t1 = *(const float4*)(sPtrG[1]);
  *(float4*)(rawW0 + sOffL[0]) = r0t0;
  *(float4*)(rawW0 + sOffL[1]) = r0t1;
  float4 rrA = *(const float4*)(sPtrG[0] + 8192);
  float4 rrB = *(const float4*)(sPtrG[1] + 8192);

  for (int ck = 0; ck < 64; ++ck) {
    // A loads for THIS chunk (issued first; consumed after gather)
    float4 av[8];
#pragma unroll
    for (int zf = 0; zf < 4; ++zf) {
      av[2 * zf]     = *(const float4*)(wfp[zf] + ck * 32);
      av[2 * zf + 1] = *(const float4*)(wfp[zf] + ck * 32 + 4);
    }
    // raw loads for chunk ck+2
    float4 rnA, rnB;
    if (ck + 2 < 64) {
      rnA = *(const float4*)(sPtrG[0] + (size_t)(ck + 2) * 8192);
      rnB = *(const float4*)(sPtrG[1] + (size_t)(ck + 2) * 8192);
    }
    // stage raw for chunk ck+1 (regs loaded last iteration; wave-private)
    if (ck + 1 < 64) {
      float* dst = ((ck + 1) & 1) ? rawW1 : rawW0;
      *(float4*)(dst + sOffL[0]) = rrA;
      *(float4*)(dst + sOffL[1]) = rrB;
    }
    // im2col gather of chunk ck (in-order DS: staged writes already ordered)
    gather((ck & 1) ? rawW1 : rawW0);
    writeB();
    // pack A fragments
    bf16x8 afv[4];
#pragma unroll
    for (int zf = 0; zf < 4; ++zf) {
      U4BF8 c;
      c.u.x = packbf(av[2 * zf].x,     av[2 * zf].y);
      c.u.y = packbf(av[2 * zf].z,     av[2 * zf].w);
      c.u.z = packbf(av[2 * zf + 1].x, av[2 * zf + 1].y);
      c.u.w = packbf(av[2 * zf + 1].z, av[2 * zf + 1].w);
      afv[zf] = c.v;
    }
    // B fragments (just written by this wave; in-order + lgkmcnt) + MFMA
    bf16x8 bfv[4];
#pragma unroll
    for (int mf = 0; mf < 4; ++mf) bfv[mf] = *(const bf16x8*)bfp[mf];
#pragma unroll
    for (int zf = 0; zf < 4; ++zf)
#pragma unroll
      for (int mf = 0; mf < 4; ++mf)
        acc[zf][mf] = __builtin_amdgcn_mfma_f32_16x16x32_bf16(afv[zf], bfv[mf], acc[zf][mf], 0, 0, 0);
    rrA = rnA;
    rrB = rnB;
  }

  // ================= block-local BN: stats -> inv/shift -> apply =============
  __syncthreads();                 // first and only block sync; reuse LDS
  float* const sums  = (float*)lds;         // [ch_local 0..63][wave 0..7]
  float* const sums2 = sums + 512;
  float* const invL  = sums2 + 512;         // [64]
  float* const shL   = invL + 64;           // [64]
#pragma unroll
  for (int zf = 0; zf < 4; ++zf) {
    float s[4], ss[4];
#pragma unroll
    for (int r = 0; r < 4; ++r) {
      s[r]  = acc[zf][0][r] + acc[zf][1][r] + acc[zf][2][r] + acc[zf][3][r];
      ss[r] = acc[zf][0][r] * acc[zf][0][r] + acc[zf][1][r] * acc[zf][1][r]
            + acc[zf][2][r] * acc[zf][2][r] + acc[zf][3][r] * acc[zf][3][r];
    }
#pragma unroll
    for (int off = 1; off <= 8; off <<= 1) {
#pragma unroll
      for (int r = 0; r < 4; ++r) {
        s[r]  += __shfl_xor(s[r], off);
        ss[r] += __shfl_xor(ss[r], off);
      }
    }
    if (llo == 0) {
#pragma unroll
      for (int r = 0; r < 4; ++r) {
        const int chl = zf * 16 + lhi * 4 + r;
        sums[chl * 8 + w]  = s[r];
        sums2[chl * 8 + w] = ss[r];
      }
    }
  }
  __syncthreads();
  if (tid < 64) {
    float sum = 0.f, sq = 0.f;
#pragma unroll
    for (int i = 0; i < 8; ++i) { sum += sums[tid * 8 + i]; sq += sums2[tid * 8 + i]; }
    const int ch = g * 256 + z0 + tid;
    const float mean = sum * (1.f / 512.f);
    const float var  = fmaf(-mean, mean, sq * (1.f / 512.f));
    const float iv   = gamma[ch] * rsqrtf(var + kEps);
    invL[tid] = iv;
    shL[tid]  = fmaf(-mean, iv, beta[ch]);
  }
  __syncthreads();

  // -------- apply BN + LeakyReLU in registers; store FINAL to fold layout
#pragma unroll
  for (int zf = 0; zf < 4; ++zf) {
    float iv[4], sh[4];
#pragma unroll
    for (int r = 0; r < 4; ++r) {
      const int chl = zf * 16 + lhi * 4 + r;
      iv[r] = invL[chl];
      sh[r] = shL[chl];
    }
    const int zch = z0 + zf * 16 + lhi * 4;       // + r below
#pragma unroll
    for (int mf = 0; mf < 4; ++mf) {
      const int mm  = w * 64 + mf * 16 + llo;     // 0..511
      const int bb  = mm >> 4;
      const int o_y = (mm >> 2) & 3;
      const int o_x = mm & 3;
      float* op = out + (((size_t)bb * 256 + zch) * 32 + hp * 4 + o_y) * 32
                      + wp * 4 + o_x;
#pragma unroll
      for (int r = 0; r < 4; ++r) {
        float y = fmaf(acc[zf][mf][r], iv[r], sh[r]);
        y = y > 0.f ? y : kLrelu * y;
        op[(size_t)r * 1024] = y;
      }
    }
  }
}

extern "C" void kernel_launch(void* const* d_in, const int* in_sizes, int n_in,
                              void* d_out, int out_size, void* d_ws, size_t ws_size,
                              hipStream_t stream) {
  const float* input  = (const float*)d_in[0];
  const float* weight = (const float*)d_in[1];
  const float* gamma  = (const float*)d_in[2];
  const float* beta   = (const float*)d_in[3];
  float* out = (float*)d_out;

  conv_bn_fused<<<256, 512, 0, stream>>>(input, weight, out, gamma, beta);
}

// Round 16
// 89.973 us; speedup vs baseline: 1.7197x; 1.7197x over previous
//
#include <hip/hip_runtime.h>

namespace {
constexpr float kLrelu = 0.2f;
constexpr float kEps   = 1e-5f;
}

typedef short bf16x8 __attribute__((ext_vector_type(8)));
typedef float f32x4  __attribute__((ext_vector_type(4)));

// LDS-only barrier: waits local ops, does NOT drain vmcnt -> global prefetch
// loads stay in flight across the barrier.
#define LDS_BARRIER() asm volatile("s_waitcnt lgkmcnt(0)\n\ts_barrier" ::: "memory")

// round-to-nearest-even f32 -> bf16 (inputs are finite)
static __device__ __forceinline__ unsigned f2bf(float x) {
  unsigned u = __float_as_uint(x);
  return (u + 0x7FFFu + ((u >> 16) & 1u)) >> 16;
}
static __device__ __forceinline__ unsigned packbf(float a, float b) {
  return f2bf(a) | (f2bf(b) << 16);
}

// FINAL (session best, verified twice at 89.5/89.8 us, absmax 0.03125):
// Fully fused: grouped conv (bf16 MFMA) + block-local BatchNorm + LeakyReLU +
// fold-layout store. Block = (g, zt): 64 z-channels x ALL 512 m (BN local).
// 256 blocks x 512 threads = 8 waves, wave tile 64z x 64m, 2 blocks/CU.
// Measured bracketing (R5-R15): occupancy/prefetch/K-split/barrier-removal/
// direct-write variants all regress or are flat; this structure is the
// empirical optimum of the in-kernel-im2col decomposition.
__global__ __launch_bounds__(512, 4) void conv_bn_fused(
    const float* __restrict__ input,   // [32,128,64,64]
    const float* __restrict__ weight,  // [16384, 2048]  (k = nc*16 + ky*4 + kx)
    float* __restrict__ out,           // [32,256,32,32] FINAL (post BN+LReLU)
    const float* __restrict__ gamma,
    const float* __restrict__ beta)
{
  // raw patch tiles: 64 patches (32 b x 2 nc) x 64 floats, row-XOR swizzle:
  //   addr(fl) = pl*64 + ((py ^ (bl&7))<<3) + px        (16 KB per buffer)
  __shared__ __align__(16) float raw0[64 * 64];
  __shared__ __align__(16) float raw1[64 * 64];
  // GEMM tiles, row = 64B (32 bf16), 16B-granule XOR swizzle (gk ^ ((row>>1)&3))
  __shared__ __align__(16) char Bs[512 * 64];     // 32 KB
  __shared__ __align__(16) char As[64 * 64];      // 4 KB

  const int bid  = blockIdx.x;
  const int orig = (bid & 7) * 32 + (bid >> 3);   // XCD-chunked (256 % 8 == 0)
  const int g    = orig >> 2;                     // group 0..63
  const int zt   = orig & 3;                      // z tile 0..3
  const int hp = g >> 3, wp = g & 7;
  const int z0 = zt * 64;

  const int tid  = threadIdx.x;
  const int lane = tid & 63;
  const int w    = tid >> 6;                      // wave 0..7, m-range = w*64
  const int llo  = lane & 15, lhi = lane >> 4;

  // -------- raw staging: two float4/thread/chunk (64 patches x 16 float4)
  const int pl_s  = tid >> 3;                     // patch 0..63
  const int f4    = tid & 7;
  const int bl_s  = pl_s >> 1;                    // b 0..31
  const int ncs_s = pl_s & 1;
  const int py_s  = f4 >> 1, h_s = f4 & 1;
  const float* const gsrc = input
      + ((size_t)bl_s * 128 + ncs_s) * 4096
      + (hp * 8 + py_s) * 64 + wp * 8 + (h_s << 2);   // 2nd load: +256 (py+4)
  const int roffA = pl_s * 64 + ((py_s ^ (bl_s & 7)) << 3) + (h_s << 2);
  const int roffB = pl_s * 64 + (((py_s + 4) ^ (bl_s & 7)) << 3) + (h_s << 2);
  float* const rd0a = raw0 + roffA;  float* const rd0b = raw0 + roffB;
  float* const rd1a = raw1 + roffA;  float* const rd1b = raw1 + roffB;

  // -------- weight staging: one task/thread: az0=tid>>3 (0..63), kq=tid&7
  const int az0 = tid >> 3;
  const int kq  = tid & 7;
  const float* const wsrc =
      weight + ((size_t)(g * 256 + z0 + az0)) * 2048 + kq * 4;
  const int aswz = (az0 >> 1) & 3;
  char* const ad0 = As + az0 * 64 + (((kq >> 1) ^ aswz) << 4) + ((kq & 1) << 3);

  // -------- row-gather: 2 tasks/thread (ncs=0,1): bl=tid>>4, oy, ky
  const int bl_g = tid >> 4;                      // 0..31
  const int oy_g = (tid >> 2) & 3;
  const int ky_g = tid & 3;
  const int iy   = 2 * oy_g - 1 + ky_g;
  const unsigned rowm = ((unsigned)iy < 8u) ? 0xFFFFFFFFu : 0u;
  const int iyc  = iy < 0 ? 0 : (iy > 7 ? 7 : iy);
  const int swzg = bl_g & 7;
  const int gro0 = (bl_g * 2 + 0) * 64 + ((iyc ^ swzg) << 3);
  const int gro1 = (bl_g * 2 + 1) * 64 + ((iyc ^ swzg) << 3);
  // B-write dsts: ml = bl*16+oy*4+ox, byte col = ncs*32 + ky*8
  char* bwd[2][4];
#pragma unroll
  for (int ncs = 0; ncs < 2; ++ncs)
#pragma unroll
    for (int ox = 0; ox < 4; ++ox) {
      const int ml = bl_g * 16 + oy_g * 4 + ox;
      const int gk = ncs * 2 + (ky_g >> 1);
      bwd[ncs][ox] = Bs + ml * 64 + ((gk ^ ((ml >> 1) & 3)) << 4) + ((ky_g & 1) << 3);
    }

  // -------- fragment read pointers
  const char* afp[4];
#pragma unroll
  for (int zf = 0; zf < 4; ++zf) {
    const int ar = zf * 16 + llo;
    afp[zf] = As + ar * 64 + ((lhi ^ ((ar >> 1) & 3)) << 4);
  }
  const char* bfp[4];
#pragma unroll
  for (int mf = 0; mf < 4; ++mf) {
    const int mr = w * 64 + mf * 16 + llo;        // 0..511
    bfp[mf] = Bs + mr * 64 + ((lhi ^ ((mr >> 1) & 3)) << 4);
  }

  f32x4 acc[4][4] = {};

  // tap selects: row[0..7] = r0.xyzw r1.xyzw; tap(ox,kx) = row[2ox-1+kx]
  uint2 ub[2][4];
  auto gather = [&](const float* rw) {
#pragma unroll
    for (int ncs = 0; ncs < 2; ++ncs) {
      const int gro = ncs ? gro1 : gro0;
      const float4 r0 = *(const float4*)(rw + gro);
      const float4 r1 = *(const float4*)(rw + gro + 4);
      uint2 t;
      t.x = packbf(0.f, r0.x) & rowm;  t.y = packbf(r0.y, r0.z) & rowm;  ub[ncs][0] = t;
      t.x = packbf(r0.y, r0.z) & rowm; t.y = packbf(r0.w, r1.x) & rowm;  ub[ncs][1] = t;
      t.x = packbf(r0.w, r1.x) & rowm; t.y = packbf(r1.y, r1.z) & rowm;  ub[ncs][2] = t;
      t.x = packbf(r1.y, r1.z) & rowm; t.y = packbf(r1.w, 0.f) & rowm;   ub[ncs][3] = t;
    }
  };
  auto writeB = [&]() {
#pragma unroll
    for (int ncs = 0; ncs < 2; ++ncs)
#pragma unroll
      for (int ox = 0; ox < 4; ++ox) *(uint2*)bwd[ncs][ox] = ub[ncs][ox];
  };
  auto domfma = [&]() {
    bf16x8 bfv[4];
#pragma unroll
    for (int mf = 0; mf < 4; ++mf) bfv[mf] = *(const bf16x8*)bfp[mf];
#pragma unroll
    for (int zf = 0; zf < 4; ++zf) {
      const bf16x8 af = *(const bf16x8*)afp[zf];
#pragma unroll
      for (int mf = 0; mf < 4; ++mf)
        acc[zf][mf] = __builtin_amdgcn_mfma_f32_16x16x32_bf16(af, bfv[mf], acc[zf][mf], 0, 0, 0);
    }
  };

  // -------- prologue: prefetch chunks 0,1; stage chunk 0 into raw0
  float4 ra0 = *(const float4*)(gsrc);
  float4 ra1 = *(const float4*)(gsrc + 256);
  float4 rb0 = *(const float4*)(gsrc + 8192);
  float4 rb1 = *(const float4*)(gsrc + 8192 + 256);
  float4 wa  = *(const float4*)(wsrc);
  float4 wb  = *(const float4*)(wsrc + 32);
  *(float4*)rd0a = ra0;
  *(float4*)rd0b = ra1;
  LDS_BARRIER();

  for (int ck = 0; ck < 64; ck += 2) {
    // ============ even chunk ck (gather raw0, stage ck+1 -> raw1) ============
    {
      uint2 a0w;
      a0w.x = packbf(wa.x, wa.y); a0w.y = packbf(wa.z, wa.w);
      if (ck + 2 < 64) {
        ra0 = *(const float4*)(gsrc + (size_t)(ck + 2) * 8192);
        ra1 = *(const float4*)(gsrc + (size_t)(ck + 2) * 8192 + 256);
        wa  = *(const float4*)(wsrc + (ck + 2) * 32);
      }
      gather(raw0);
      LDS_BARRIER();               // prev MFMAs + this gather done reading LDS
      *(uint2*)ad0 = a0w;
      writeB();
      *(float4*)rd1a = rb0;        // stage chunk ck+1 (loaded 2 phases ago)
      *(float4*)rd1b = rb1;
      LDS_BARRIER();               // tiles + raw1 visible
      domfma();
    }
    // ============ odd chunk ck+1 (gather raw1, stage ck+2 -> raw0) ===========
    {
      uint2 a0w;
      a0w.x = packbf(wb.x, wb.y); a0w.y = packbf(wb.z, wb.w);
      if (ck + 3 < 64) {
        rb0 = *(const float4*)(gsrc + (size_t)(ck + 3) * 8192);
        rb1 = *(const float4*)(gsrc + (size_t)(ck + 3) * 8192 + 256);
        wb  = *(const float4*)(wsrc + (ck + 3) * 32);
      }
      gather(raw1);
      LDS_BARRIER();
      *(uint2*)ad0 = a0w;
      writeB();
      if (ck + 2 < 64) { *(float4*)rd0a = ra0; *(float4*)rd0b = ra1; }
      LDS_BARRIER();
      domfma();
    }
  }

  // ================= block-local BN: stats -> inv/shift -> apply =============
  __syncthreads();                 // all waves done with tiles; reuse raw0/raw1
  float* const sums  = (float*)raw0;        // [ch_local 0..63][wave 0..7]
  float* const sums2 = sums + 512;
#pragma unroll
  for (int zf = 0; zf < 4; ++zf) {
    float s[4], ss[4];
#pragma unroll
    for (int r = 0; r < 4; ++r) {
      s[r]  = acc[zf][0][r] + acc[zf][1][r] + acc[zf][2][r] + acc[zf][3][r];
      ss[r] = acc[zf][0][r] * acc[zf][0][r] + acc[zf][1][r] * acc[zf][1][r]
            + acc[zf][2][r] * acc[zf][2][r] + acc[zf][3][r] * acc[zf][3][r];
    }
#pragma unroll
    for (int off = 1; off <= 8; off <<= 1) {
#pragma unroll
      for (int r = 0; r < 4; ++r) {
        s[r]  += __shfl_xor(s[r], off);
        ss[r] += __shfl_xor(ss[r], off);
      }
    }
    if (llo == 0) {
#pragma unroll
      for (int r = 0; r < 4; ++r) {
        const int chl = zf * 16 + lhi * 4 + r;
        sums[chl * 8 + w]  = s[r];
        sums2[chl * 8 + w] = ss[r];
      }
    }
  }
  __syncthreads();
  float* const invL = (float*)raw1;         // [64]
  float* const shL  = invL + 64;            // [64]
  if (tid < 64) {
    float sum = 0.f, sq = 0.f;
#pragma unroll
    for (int i = 0; i < 8; ++i) { sum += sums[tid * 8 + i]; sq += sums2[tid * 8 + i]; }
    const int ch = g * 256 + z0 + tid;
    const float mean = sum * (1.f / 512.f);
    const float var  = fmaf(-mean, mean, sq * (1.f / 512.f));
    const float iv   = gamma[ch] * rsqrtf(var + kEps);
    invL[tid] = iv;
    shL[tid]  = fmaf(-mean, iv, beta[ch]);
  }
  __syncthreads();

  // -------- apply BN + LeakyReLU in registers; store FINAL to fold layout
#pragma unroll
  for (int zf = 0; zf < 4; ++zf) {
    float iv[4], sh[4];
#pragma unroll
    for (int r = 0; r < 4; ++r) {
      const int chl = zf * 16 + lhi * 4 + r;
      iv[r] = invL[chl];
      sh[r] = shL[chl];
    }
    const int zch = z0 + zf * 16 + lhi * 4;       // + r below
#pragma unroll
    for (int mf = 0; mf < 4; ++mf) {
      const int mm  = w * 64 + mf * 16 + llo;     // 0..511
      const int bb  = mm >> 4;
      const int o_y = (mm >> 2) & 3;
      const int o_x = mm & 3;
      float* op = out + (((size_t)bb * 256 + zch) * 32 + hp * 4 + o_y) * 32
                      + wp * 4 + o_x;
#pragma unroll
      for (int r = 0; r < 4; ++r) {
        float y = fmaf(acc[zf][mf][r], iv[r], sh[r]);
        y = y > 0.f ? y : kLrelu * y;
        op[(size_t)r * 1024] = y;
      }
    }
  }
}

extern "C" void kernel_launch(void* const* d_in, const int* in_sizes, int n_in,
                              void* d_out, int out_size, void* d_ws, size_t ws_size,
                              hipStream_t stream) {
  const float* input  = (const float*)d_in[0];
  const float* weight = (const float*)d_in[1];
  const float* gamma  = (const float*)d_in[2];
  const float* beta   = (const float*)d_in[3];
  float* out = (float*)d_out;

  conv_bn_fused<<<256, 512, 0, stream>>>(input, weight, out, gamma, beta);
}